// Round 1
// baseline (702.708 us; speedup 1.0000x reference)
//
#include <hip/hip_runtime.h>
#include <hip/hip_bf16.h>
#include <cstddef>

// Problem dims
#define H   512
#define E   256
#define V   32000
#define L   1024
#define B   64
#define KX  768      // E + H
#define G4  2048     // 4*H
#define M_TOT 65536  // L*B

// ---------------------------------------------------------------------------
// K0: build xprevT[k][b]: k<256 = emb[tok[b]][k]; k<768 = last_output_context;
//     k<1280 = last_hidden (h_prev).  Transposed (b fastest) for lane=b reads.
// ---------------------------------------------------------------------------
__global__ __launch_bounds__(256) void k_build(const int* __restrict__ inp,
                                               const float* __restrict__ loc,
                                               const float* __restrict__ hprev,
                                               const float* __restrict__ emb,
                                               float* __restrict__ xprevT) {
    int gid = blockIdx.x * 256 + threadIdx.x;           // 0 .. 1280*64
    int k = gid >> 6, b = gid & 63;
    float v;
    if (k < 256)      v = emb[(size_t)inp[b] * E + k];
    else if (k < 768) v = loc[b * H + (k - 256)];
    else              v = hprev[b * H + (k - 768)];
    xprevT[gid] = v;
}

// ---------------------------------------------------------------------------
// K1: LSTM cell. grid = 512 blocks (u = hidden unit), 4 waves = 4 gates,
//     lane = b. Wave w computes gates[j = w*512+u][b]; epilogue does c,h.
// ---------------------------------------------------------------------------
__global__ __launch_bounds__(256) void k_lstm(const float* __restrict__ W_ih,
                                              const float* __restrict__ W_hh,
                                              const float* __restrict__ b_ih,
                                              const float* __restrict__ b_hh,
                                              const float* __restrict__ xprevT,
                                              const float* __restrict__ cprev,
                                              float* __restrict__ h_out,
                                              float* __restrict__ c_out,
                                              float* __restrict__ hnewT) {
    int u = blockIdx.x;
    int w = threadIdx.x >> 6;
    int b = threadIdx.x & 63;
    int j = w * 512 + u;
    float acc = b_ih[j] + b_hh[j];
    const float* Wr = &W_ih[(size_t)j * KX];
    for (int k = 0; k < KX; k += 4) {
        float4 wv = *reinterpret_cast<const float4*>(&Wr[k]);
        acc += wv.x * xprevT[(k + 0) * 64 + b];
        acc += wv.y * xprevT[(k + 1) * 64 + b];
        acc += wv.z * xprevT[(k + 2) * 64 + b];
        acc += wv.w * xprevT[(k + 3) * 64 + b];
    }
    const float* Wr2 = &W_hh[(size_t)j * H];
    const float* hT = &xprevT[KX * 64];
    for (int k = 0; k < H; k += 4) {
        float4 wv = *reinterpret_cast<const float4*>(&Wr2[k]);
        acc += wv.x * hT[(k + 0) * 64 + b];
        acc += wv.y * hT[(k + 1) * 64 + b];
        acc += wv.z * hT[(k + 2) * 64 + b];
        acc += wv.w * hT[(k + 3) * 64 + b];
    }
    __shared__ float gs[4][64];
    gs[w][b] = acc;
    __syncthreads();
    if (threadIdx.x < 64) {
        float ig = 1.f / (1.f + __expf(-gs[0][b]));
        float fg = 1.f / (1.f + __expf(-gs[1][b]));
        float gg = tanhf(gs[2][b]);
        float og = 1.f / (1.f + __expf(-gs[3][b]));
        float c = fg * cprev[b * H + u] + ig * gg;
        float h = og * tanhf(c);
        c_out[b * H + u] = c;
        h_out[b * H + u] = h;
        hnewT[u * 64 + b] = h;
    }
}

// ---------------------------------------------------------------------------
// K2: hW_jb[j][b] = b_attn[j] + sum_k h[b][k] * W_attn[j][k]  (first H cols)
// ---------------------------------------------------------------------------
__global__ __launch_bounds__(256) void k_hw(const float* __restrict__ W_attn,
                                            const float* __restrict__ b_attn,
                                            const float* __restrict__ hT,
                                            float* __restrict__ hW_jb) {
    int j = blockIdx.x * 4 + (threadIdx.x >> 6);
    int b = threadIdx.x & 63;
    float acc = b_attn[j];
    const float* Wr = &W_attn[(size_t)j * (2 * H)];
    for (int k = 0; k < H; k += 4) {
        float4 wv = *reinterpret_cast<const float4*>(&Wr[k]);
        acc += wv.x * hT[(k + 0) * 64 + b];
        acc += wv.y * hT[(k + 1) * 64 + b];
        acc += wv.z * hT[(k + 2) * 64 + b];
        acc += wv.w * hT[(k + 3) * 64 + b];
    }
    hW_jb[j * 64 + b] = acc;
}

// ---------------------------------------------------------------------------
// K3: energy GEMM (fp32). C[m][j] = enc[m][:] . Wa2[j][:], Wa2 = W_attn[:,H:].
// Tile 64(m) x 64(j), KT=32. Each M-tile is one l (m = l*64+b, b = tm).
// Epilogue: e = acc + hW_jb[j][b]; partial_e[nb][m] += tanh(e)*beta[j].
// ---------------------------------------------------------------------------
#define KT 32
__global__ __launch_bounds__(256) void k_energy(const float* __restrict__ enc,
                                                const float* __restrict__ W_attn,
                                                const float* __restrict__ hW_jb,
                                                const float* __restrict__ beta,
                                                float* __restrict__ partial_e) {
    const int mt = blockIdx.x;          // 0..1023  (= l)
    const int nb = blockIdx.y;          // 0..7
    const int tid = threadIdx.x;
    const int tx = tid & 15;            // j group
    const int ty = tid >> 4;            // m group
    __shared__ float As[KT][68];
    __shared__ float Bs[KT][68];
    float acc[4][4] = {};
    const int m0 = mt * 64;
    const int j0 = nb * 64;
    for (int k0 = 0; k0 < H; k0 += KT) {
        #pragma unroll
        for (int it = 0; it < 2; ++it) {
            int idx = tid + it * 256;     // 0..511 float4 slots
            int r  = idx >> 3;            // row 0..63
            int c4 = idx & 7;             // float4 col 0..7
            float4 a = *reinterpret_cast<const float4*>(
                &enc[(size_t)(m0 + r) * H + k0 + c4 * 4]);
            As[c4 * 4 + 0][r] = a.x; As[c4 * 4 + 1][r] = a.y;
            As[c4 * 4 + 2][r] = a.z; As[c4 * 4 + 3][r] = a.w;
            float4 w = *reinterpret_cast<const float4*>(
                &W_attn[(size_t)(j0 + r) * (2 * H) + H + k0 + c4 * 4]);
            Bs[c4 * 4 + 0][r] = w.x; Bs[c4 * 4 + 1][r] = w.y;
            Bs[c4 * 4 + 2][r] = w.z; Bs[c4 * 4 + 3][r] = w.w;
        }
        __syncthreads();
        #pragma unroll
        for (int k = 0; k < KT; ++k) {
            float4 a4 = *reinterpret_cast<const float4*>(&As[k][ty * 4]);
            float4 b4 = *reinterpret_cast<const float4*>(&Bs[k][tx * 4]);
            float a[4] = {a4.x, a4.y, a4.z, a4.w};
            float b[4] = {b4.x, b4.y, b4.z, b4.w};
            #pragma unroll
            for (int i = 0; i < 4; ++i)
                #pragma unroll
                for (int j = 0; j < 4; ++j)
                    acc[i][j] += a[i] * b[j];
        }
        __syncthreads();
    }
    // epilogue: b = tm (tile is one l, all 64 b)
    float psum[4] = {0.f, 0.f, 0.f, 0.f};
    #pragma unroll
    for (int j = 0; j < 4; ++j) {
        int jj = j0 + tx * 4 + j;
        float bet = beta[jj];
        #pragma unroll
        for (int i = 0; i < 4; ++i) {
            int b = ty * 4 + i;
            float e = acc[i][j] + hW_jb[jj * 64 + b];
            psum[i] += tanhf(e) * bet;
        }
    }
    // reduce over tx (16 lanes within each wave-quarter)
    __shared__ float red[64];
    #pragma unroll
    for (int i = 0; i < 4; ++i) {
        float v = psum[i];
        #pragma unroll
        for (int s = 1; s < 16; s <<= 1) v += __shfl_xor(v, s);
        if (tx == 0) red[ty * 4 + i] = v;
    }
    __syncthreads();
    if (tid < 64) partial_e[(size_t)nb * M_TOT + m0 + tid] = red[tid];
}

// ---------------------------------------------------------------------------
// K4: softmax over l per b.  e[l] = sum_nb partial_e[nb][l*64+b]
// ---------------------------------------------------------------------------
__global__ __launch_bounds__(256) void k_softmax_l(const float* __restrict__ partial_e,
                                                   float* __restrict__ attn_w) {
    int b = blockIdx.x;
    int tid = threadIdx.x;
    float el[4];
    float m = -1e30f;
    #pragma unroll
    for (int i = 0; i < 4; ++i) {
        int l = i * 256 + tid;
        float e = 0.f;
        #pragma unroll
        for (int nb = 0; nb < 8; ++nb)
            e += partial_e[(size_t)nb * M_TOT + l * 64 + b];
        el[i] = e;
        m = fmaxf(m, e);
    }
    #pragma unroll
    for (int s = 1; s < 64; s <<= 1) m = fmaxf(m, __shfl_xor(m, s));
    __shared__ float redm[4];
    if ((tid & 63) == 0) redm[tid >> 6] = m;
    __syncthreads();
    m = fmaxf(fmaxf(redm[0], redm[1]), fmaxf(redm[2], redm[3]));
    float s = 0.f;
    #pragma unroll
    for (int i = 0; i < 4; ++i) { el[i] = __expf(el[i] - m); s += el[i]; }
    #pragma unroll
    for (int sh = 1; sh < 64; sh <<= 1) s += __shfl_xor(s, sh);
    __shared__ float reds[4];
    if ((tid & 63) == 0) reds[tid >> 6] = s;
    __syncthreads();
    s = reds[0] + reds[1] + reds[2] + reds[3];
    float inv = 1.f / s;
    #pragma unroll
    for (int i = 0; i < 4; ++i)
        attn_w[(i * 256 + tid) * 64 + b] = el[i] * inv;
}

// ---------------------------------------------------------------------------
// K5: context partials over l chunks. grid (32 chunks, 64 b), thread = 2 h.
// ---------------------------------------------------------------------------
__global__ __launch_bounds__(256) void k_ctx_part(const float* __restrict__ attn_w,
                                                  const float* __restrict__ enc,
                                                  float* __restrict__ ctx_part) {
    int chunk = blockIdx.x, b = blockIdx.y;
    int h = threadIdx.x * 2;
    float2 acc = {0.f, 0.f};
    for (int i = 0; i < 32; ++i) {
        int l = chunk * 32 + i;
        float w = attn_w[l * 64 + b];
        float2 e2 = *reinterpret_cast<const float2*>(
            &enc[((size_t)l * 64 + b) * H + h]);
        acc.x += w * e2.x;
        acc.y += w * e2.y;
    }
    *reinterpret_cast<float2*>(&ctx_part[((size_t)(chunk * 64 + b)) * H + h]) = acc;
}

__global__ __launch_bounds__(256) void k_ctx_reduce(const float* __restrict__ ctx_part,
                                                    float* __restrict__ ctxT) {
    int gid = blockIdx.x * 256 + threadIdx.x;   // 0..32767
    int b = gid >> 9, h = gid & 511;
    float s = 0.f;
    for (int c = 0; c < 32; ++c)
        s += ctx_part[((size_t)(c * 64 + b)) * H + h];
    ctxT[h * 64 + b] = s;
}

// ---------------------------------------------------------------------------
// K6: co[b][j] = tanh([h | ctx] . W_oc[j] + b_oc[j])
// ---------------------------------------------------------------------------
__global__ __launch_bounds__(256) void k_co(const float* __restrict__ W_oc,
                                            const float* __restrict__ b_oc,
                                            const float* __restrict__ hT,
                                            const float* __restrict__ ctxT,
                                            float* __restrict__ co_out) {
    int j = blockIdx.x * 4 + (threadIdx.x >> 6);
    int b = threadIdx.x & 63;
    float acc = b_oc[j];
    const float* Wr = &W_oc[(size_t)j * (2 * H)];
    for (int k = 0; k < H; k += 4) {
        float4 wv = *reinterpret_cast<const float4*>(&Wr[k]);
        acc += wv.x * hT[(k + 0) * 64 + b];
        acc += wv.y * hT[(k + 1) * 64 + b];
        acc += wv.z * hT[(k + 2) * 64 + b];
        acc += wv.w * hT[(k + 3) * 64 + b];
    }
    const float* Wr2 = Wr + H;
    for (int k = 0; k < H; k += 4) {
        float4 wv = *reinterpret_cast<const float4*>(&Wr2[k]);
        acc += wv.x * ctxT[(k + 0) * 64 + b];
        acc += wv.y * ctxT[(k + 1) * 64 + b];
        acc += wv.z * ctxT[(k + 2) * 64 + b];
        acc += wv.w * ctxT[(k + 3) * 64 + b];
    }
    co_out[b * H + j] = tanhf(acc);
}

// ---------------------------------------------------------------------------
// K7: logits GEMM (fp32): logits[b][j] = co[b][:].W_out[j][:] + b_out[j]
// Tile 64(b) x 64(j), KT=32, grid = 500.
// ---------------------------------------------------------------------------
__global__ __launch_bounds__(256) void k_logits(const float* __restrict__ co,
                                                const float* __restrict__ W_out,
                                                const float* __restrict__ b_out,
                                                float* __restrict__ logits) {
    const int nb = blockIdx.x;          // 0..499
    const int tid = threadIdx.x;
    const int tx = tid & 15;
    const int ty = tid >> 4;
    __shared__ float As[KT][68];
    __shared__ float Bs[KT][68];
    float acc[4][4] = {};
    const int j0 = nb * 64;
    for (int k0 = 0; k0 < H; k0 += KT) {
        #pragma unroll
        for (int it = 0; it < 2; ++it) {
            int idx = tid + it * 256;
            int r  = idx >> 3;
            int c4 = idx & 7;
            float4 a = *reinterpret_cast<const float4*>(
                &co[(size_t)r * H + k0 + c4 * 4]);
            As[c4 * 4 + 0][r] = a.x; As[c4 * 4 + 1][r] = a.y;
            As[c4 * 4 + 2][r] = a.z; As[c4 * 4 + 3][r] = a.w;
            float4 w = *reinterpret_cast<const float4*>(
                &W_out[(size_t)(j0 + r) * H + k0 + c4 * 4]);
            Bs[c4 * 4 + 0][r] = w.x; Bs[c4 * 4 + 1][r] = w.y;
            Bs[c4 * 4 + 2][r] = w.z; Bs[c4 * 4 + 3][r] = w.w;
        }
        __syncthreads();
        #pragma unroll
        for (int k = 0; k < KT; ++k) {
            float4 a4 = *reinterpret_cast<const float4*>(&As[k][ty * 4]);
            float4 b4 = *reinterpret_cast<const float4*>(&Bs[k][tx * 4]);
            float a[4] = {a4.x, a4.y, a4.z, a4.w};
            float b[4] = {b4.x, b4.y, b4.z, b4.w};
            #pragma unroll
            for (int i = 0; i < 4; ++i)
                #pragma unroll
                for (int j = 0; j < 4; ++j)
                    acc[i][j] += a[i] * b[j];
        }
        __syncthreads();
    }
    #pragma unroll
    for (int i = 0; i < 4; ++i) {
        int b = ty * 4 + i;
        float4 v;
        v.x = acc[i][0] + b_out[j0 + tx * 4 + 0];
        v.y = acc[i][1] + b_out[j0 + tx * 4 + 1];
        v.z = acc[i][2] + b_out[j0 + tx * 4 + 2];
        v.w = acc[i][3] + b_out[j0 + tx * 4 + 3];
        *reinterpret_cast<float4*>(&logits[(size_t)b * V + j0 + tx * 4]) = v;
    }
}

// ---------------------------------------------------------------------------
// K8: log_softmax per b over V. 64 blocks x 1024 threads.
// ---------------------------------------------------------------------------
__global__ __launch_bounds__(1024) void k_logsm(const float* __restrict__ logits,
                                                float* __restrict__ out) {
    int b = blockIdx.x;
    int tid = threadIdx.x;
    const float* row = &logits[(size_t)b * V];
    float m = -1e30f;
    for (int i = tid; i < V; i += 1024) m = fmaxf(m, row[i]);
    #pragma unroll
    for (int s = 1; s < 64; s <<= 1) m = fmaxf(m, __shfl_xor(m, s));
    __shared__ float redm[16];
    if ((tid & 63) == 0) redm[tid >> 6] = m;
    __syncthreads();
    m = redm[0];
    #pragma unroll
    for (int i = 1; i < 16; ++i) m = fmaxf(m, redm[i]);
    float s = 0.f;
    for (int i = tid; i < V; i += 1024) s += __expf(row[i] - m);
    #pragma unroll
    for (int sh = 1; sh < 64; sh <<= 1) s += __shfl_xor(s, sh);
    __shared__ float reds[16];
    if ((tid & 63) == 0) reds[tid >> 6] = s;
    __syncthreads();
    s = reds[0];
    #pragma unroll
    for (int i = 1; i < 16; ++i) s += reds[i];
    float lse = m + __logf(s);
    for (int i = tid; i < V; i += 1024)
        out[(size_t)b * V + i] = row[i] - lse;
}

// ---------------------------------------------------------------------------
extern "C" void kernel_launch(void* const* d_in, const int* in_sizes, int n_in,
                              void* d_out, int out_size, void* d_ws, size_t ws_size,
                              hipStream_t stream) {
    const int*   inp    = (const int*)  d_in[0];
    const float* loc    = (const float*)d_in[1];
    const float* hprev  = (const float*)d_in[2];
    const float* cprev  = (const float*)d_in[3];
    const float* enc    = (const float*)d_in[4];
    const float* emb    = (const float*)d_in[5];
    const float* W_ih   = (const float*)d_in[6];
    const float* W_hh   = (const float*)d_in[7];
    const float* b_ih   = (const float*)d_in[8];
    const float* b_hh   = (const float*)d_in[9];
    const float* W_attn = (const float*)d_in[10];
    const float* b_attn = (const float*)d_in[11];
    const float* beta   = (const float*)d_in[12];
    const float* W_oc   = (const float*)d_in[13];
    const float* b_oc   = (const float*)d_in[14];
    const float* W_out  = (const float*)d_in[15];
    const float* b_out  = (const float*)d_in[16];

    float* out = (float*)d_out;
    float* out_co = out + (size_t)B * V;                 // 2,048,000
    float* out_h  = out_co + B * H;                      // +32768
    float* out_c  = out_h  + B * H;                      // +32768

    float* ws = (float*)d_ws;
    float* xprevT = ws;                                  // 81920
    float* hnewT  = xprevT + 1280 * 64;                  // 32768
    float* hW     = hnewT  + H * 64;                     // 32768
    float* pe     = hW     + H * 64;                     // 8*65536
    float* attnw  = pe     + 8 * M_TOT;                  // 65536
    float* ctxp   = attnw  + M_TOT;                      // 32*64*512
    float* ctxT   = ctxp   + 32 * 64 * H;                // 32768
    float* logits = ctxT   + H * 64;                     // 64*32000

    k_build <<<320, 256, 0, stream>>>(inp, loc, hprev, emb, xprevT);
    k_lstm  <<<512, 256, 0, stream>>>(W_ih, W_hh, b_ih, b_hh, xprevT, cprev,
                                      out_h, out_c, hnewT);
    k_hw    <<<128, 256, 0, stream>>>(W_attn, b_attn, hnewT, hW);
    k_energy<<<dim3(1024, 8), 256, 0, stream>>>(enc, W_attn, hW, beta, pe);
    k_softmax_l<<<64, 256, 0, stream>>>(pe, attnw);
    k_ctx_part <<<dim3(32, 64), 256, 0, stream>>>(attnw, enc, ctxp);
    k_ctx_reduce<<<128, 256, 0, stream>>>(ctxp, ctxT);
    k_co    <<<128, 256, 0, stream>>>(W_oc, b_oc, hnewT, ctxT, out_co);
    k_logits<<<500, 256, 0, stream>>>(out_co, W_out, b_out, logits);
    k_logsm <<<64, 1024, 0, stream>>>(logits, out);
}

// Round 2
// 351.278 us; speedup vs baseline: 2.0004x; 2.0004x over previous
//
#include <hip/hip_runtime.h>
#include <hip/hip_bf16.h>
#include <cstddef>

// Problem dims
#define H   512
#define E   256
#define V   32000
#define L   1024
#define B   64
#define KX  768      // E + H
#define M_TOT 65536  // L*B

typedef __attribute__((ext_vector_type(8))) short short8v;
typedef __attribute__((ext_vector_type(4))) float f32x4;

union fu32 { float f; unsigned u; };

__device__ __forceinline__ unsigned short f2bf(float x) {
    fu32 v; v.f = x;
    unsigned r = v.u + 0x7FFFu + ((v.u >> 16) & 1u);   // RNE
    return (unsigned short)(r >> 16);
}
__device__ __forceinline__ float bf2f(unsigned short b) {
    fu32 v; v.u = ((unsigned)b) << 16; return v.f;
}

// ---------------------------------------------------------------------------
// K0: build xprevT[k][b]
// ---------------------------------------------------------------------------
__global__ __launch_bounds__(256) void k_build(const int* __restrict__ inp,
                                               const float* __restrict__ loc,
                                               const float* __restrict__ hprev,
                                               const float* __restrict__ emb,
                                               float* __restrict__ xprevT) {
    int gid = blockIdx.x * 256 + threadIdx.x;
    int k = gid >> 6, b = gid & 63;
    float v;
    if (k < 256)      v = emb[(size_t)inp[b] * E + k];
    else if (k < 768) v = loc[b * H + (k - 256)];
    else              v = hprev[b * H + (k - 768)];
    xprevT[gid] = v;
}

// ---------------------------------------------------------------------------
// K1: LSTM cell (fp32, unchanged)
// ---------------------------------------------------------------------------
__global__ __launch_bounds__(256) void k_lstm(const float* __restrict__ W_ih,
                                              const float* __restrict__ W_hh,
                                              const float* __restrict__ b_ih,
                                              const float* __restrict__ b_hh,
                                              const float* __restrict__ xprevT,
                                              const float* __restrict__ cprev,
                                              float* __restrict__ h_out,
                                              float* __restrict__ c_out,
                                              float* __restrict__ hnewT) {
    int u = blockIdx.x;
    int w = threadIdx.x >> 6;
    int b = threadIdx.x & 63;
    int j = w * 512 + u;
    float acc = b_ih[j] + b_hh[j];
    const float* Wr = &W_ih[(size_t)j * KX];
    for (int k = 0; k < KX; k += 4) {
        float4 wv = *reinterpret_cast<const float4*>(&Wr[k]);
        acc += wv.x * xprevT[(k + 0) * 64 + b];
        acc += wv.y * xprevT[(k + 1) * 64 + b];
        acc += wv.z * xprevT[(k + 2) * 64 + b];
        acc += wv.w * xprevT[(k + 3) * 64 + b];
    }
    const float* Wr2 = &W_hh[(size_t)j * H];
    const float* hT = &xprevT[KX * 64];
    for (int k = 0; k < H; k += 4) {
        float4 wv = *reinterpret_cast<const float4*>(&Wr2[k]);
        acc += wv.x * hT[(k + 0) * 64 + b];
        acc += wv.y * hT[(k + 1) * 64 + b];
        acc += wv.z * hT[(k + 2) * 64 + b];
        acc += wv.w * hT[(k + 3) * 64 + b];
    }
    __shared__ float gs[4][64];
    gs[w][b] = acc;
    __syncthreads();
    if (threadIdx.x < 64) {
        float ig = 1.f / (1.f + __expf(-gs[0][b]));
        float fg = 1.f / (1.f + __expf(-gs[1][b]));
        float gg = tanhf(gs[2][b]);
        float og = 1.f / (1.f + __expf(-gs[3][b]));
        float c = fg * cprev[b * H + u] + ig * gg;
        float h = og * tanhf(c);
        c_out[b * H + u] = c;
        h_out[b * H + u] = h;
        hnewT[u * 64 + b] = h;
    }
}

// ---------------------------------------------------------------------------
// K2: hW_jb[j][b] = b_attn[j] + sum_k h[b][k] * W_attn[j][k]
// ---------------------------------------------------------------------------
__global__ __launch_bounds__(256) void k_hw(const float* __restrict__ W_attn,
                                            const float* __restrict__ b_attn,
                                            const float* __restrict__ hT,
                                            float* __restrict__ hW_jb) {
    int j = blockIdx.x * 4 + (threadIdx.x >> 6);
    int b = threadIdx.x & 63;
    float acc = b_attn[j];
    const float* Wr = &W_attn[(size_t)j * (2 * H)];
    for (int k = 0; k < H; k += 4) {
        float4 wv = *reinterpret_cast<const float4*>(&Wr[k]);
        acc += wv.x * hT[(k + 0) * 64 + b];
        acc += wv.y * hT[(k + 1) * 64 + b];
        acc += wv.z * hT[(k + 2) * 64 + b];
        acc += wv.w * hT[(k + 3) * 64 + b];
    }
    hW_jb[j * 64 + b] = acc;
}

// ---------------------------------------------------------------------------
// K3: energy via split-bf16 MFMA.
//   C[m][j] = enc[m][:] . Wa2[j][:]  (Wa2 = W_attn[:, H:]) split hi/lo bf16,
//   acc fp32, 3 MFMAs (hh + hl + lh).  Block = 128 rows, loops 4 j-tiles of
//   128, K=512 in steps of 32.  Epilogue: psum[m] += tanh(C+hW[j][b])*beta[j]
//   reduced in-block -> energy[m].
// LDS tiles [row][k] bf16 pitch 40 (32 + 8 pad): conflict-optimal for b128.
// ---------------------------------------------------------------------------
#define BKE 32
#define PITCH 40

__global__ __launch_bounds__(256, 2) void k_energy_mfma(
        const float* __restrict__ enc,
        const float* __restrict__ W_attn,
        const float* __restrict__ hW,
        const float* __restrict__ beta,
        float* __restrict__ energy) {
    __shared__ unsigned short Ah[128 * PITCH];
    __shared__ unsigned short Al[128 * PITCH];
    __shared__ unsigned short Bh[128 * PITCH];
    __shared__ unsigned short Bl[128 * PITCH];
    __shared__ float red[2][128];

    const int tid  = threadIdx.x;
    const int lane = tid & 63;
    const int wave = tid >> 6;
    const int wm = wave >> 1;           // 0..1 : m-half
    const int wn = wave & 1;            // 0..1 : n-half
    const int m0 = blockIdx.x * 128;

    const int srow = tid >> 2;          // 0..63 staging row
    const int skc  = tid & 3;           // 0..3  staging k-chunk (8 floats)

    float psum[4][4];                   // [mf][r]
    #pragma unroll
    for (int i = 0; i < 4; ++i)
        #pragma unroll
        for (int r = 0; r < 4; ++r) psum[i][r] = 0.f;

    for (int jt = 0; jt < 4; ++jt) {
        const int j0 = jt * 128;
        f32x4 acc[4][4];
        #pragma unroll
        for (int i = 0; i < 4; ++i)
            #pragma unroll
            for (int j = 0; j < 4; ++j) acc[i][j] = (f32x4){0.f, 0.f, 0.f, 0.f};

        for (int k0 = 0; k0 < H; k0 += BKE) {
            __syncthreads();            // previous iter's reads done
            // ---- stage A (enc rows) and B (W_attn rows, col offset H) ----
            #pragma unroll
            for (int p = 0; p < 2; ++p) {
                int row = p * 64 + srow;
                {
                    const float* src = &enc[(size_t)(m0 + row) * H + k0 + skc * 8];
                    float4 x0 = *reinterpret_cast<const float4*>(src);
                    float4 x1 = *reinterpret_cast<const float4*>(src + 4);
                    float xs[8] = {x0.x, x0.y, x0.z, x0.w, x1.x, x1.y, x1.z, x1.w};
                    union { short8v v; unsigned short u[8]; } hi, lo;
                    #pragma unroll
                    for (int i = 0; i < 8; ++i) {
                        unsigned short hb = f2bf(xs[i]);
                        hi.u[i] = hb;
                        lo.u[i] = f2bf(xs[i] - bf2f(hb));
                    }
                    int off = row * PITCH + skc * 8;
                    *reinterpret_cast<short8v*>(&Ah[off]) = hi.v;
                    *reinterpret_cast<short8v*>(&Al[off]) = lo.v;
                }
                {
                    const float* src = &W_attn[(size_t)(j0 + row) * (2 * H) + H + k0 + skc * 8];
                    float4 x0 = *reinterpret_cast<const float4*>(src);
                    float4 x1 = *reinterpret_cast<const float4*>(src + 4);
                    float xs[8] = {x0.x, x0.y, x0.z, x0.w, x1.x, x1.y, x1.z, x1.w};
                    union { short8v v; unsigned short u[8]; } hi, lo;
                    #pragma unroll
                    for (int i = 0; i < 8; ++i) {
                        unsigned short hb = f2bf(xs[i]);
                        hi.u[i] = hb;
                        lo.u[i] = f2bf(xs[i] - bf2f(hb));
                    }
                    int off = row * PITCH + skc * 8;
                    *reinterpret_cast<short8v*>(&Bh[off]) = hi.v;
                    *reinterpret_cast<short8v*>(&Bl[off]) = lo.v;
                }
            }
            __syncthreads();
            // ---- fragments + MFMA ----
            const int fr = lane & 15;          // row within fragment
            const int kb = (lane >> 4) * 8;    // k offset within fragment
            short8v a_h[4], a_l[4], b_h[4], b_l[4];
            #pragma unroll
            for (int mf = 0; mf < 4; ++mf) {
                int off = (wm * 64 + mf * 16 + fr) * PITCH + kb;
                a_h[mf] = *reinterpret_cast<const short8v*>(&Ah[off]);
                a_l[mf] = *reinterpret_cast<const short8v*>(&Al[off]);
            }
            #pragma unroll
            for (int nf = 0; nf < 4; ++nf) {
                int off = (wn * 64 + nf * 16 + fr) * PITCH + kb;
                b_h[nf] = *reinterpret_cast<const short8v*>(&Bh[off]);
                b_l[nf] = *reinterpret_cast<const short8v*>(&Bl[off]);
            }
            #pragma unroll
            for (int mf = 0; mf < 4; ++mf)
                #pragma unroll
                for (int nf = 0; nf < 4; ++nf) {
                    acc[mf][nf] = __builtin_amdgcn_mfma_f32_16x16x32_bf16(
                        a_h[mf], b_h[nf], acc[mf][nf], 0, 0, 0);
                    acc[mf][nf] = __builtin_amdgcn_mfma_f32_16x16x32_bf16(
                        a_h[mf], b_l[nf], acc[mf][nf], 0, 0, 0);
                    acc[mf][nf] = __builtin_amdgcn_mfma_f32_16x16x32_bf16(
                        a_l[mf], b_h[nf], acc[mf][nf], 0, 0, 0);
                }
        }
        // ---- epilogue: psum += tanh(acc + hW[j][b]) * beta[j] ----
        #pragma unroll
        for (int nf = 0; nf < 4; ++nf) {
            int jj = j0 + wn * 64 + nf * 16 + (lane & 15);
            float bet = beta[jj];
            #pragma unroll
            for (int mf = 0; mf < 4; ++mf) {
                int b_base = (wm * 64 + mf * 16 + (lane >> 4) * 4) & 63;
                float4 hw4 = *reinterpret_cast<const float4*>(&hW[jj * 64 + b_base]);
                float hwv[4] = {hw4.x, hw4.y, hw4.z, hw4.w};
                #pragma unroll
                for (int r = 0; r < 4; ++r) {
                    float e = acc[mf][nf][r] + hwv[r];
                    float ex = __expf(2.f * e);
                    psum[mf][r] += bet * (1.f - 2.f / (ex + 1.f));
                }
            }
        }
    }
    // ---- reduce over the 16 lanes sharing a row (lane&15 axis) ----
    #pragma unroll
    for (int mf = 0; mf < 4; ++mf)
        #pragma unroll
        for (int r = 0; r < 4; ++r) {
            float v = psum[mf][r];
            v += __shfl_xor(v, 1);
            v += __shfl_xor(v, 2);
            v += __shfl_xor(v, 4);
            v += __shfl_xor(v, 8);
            psum[mf][r] = v;
        }
    __syncthreads();
    if ((lane & 15) == 0) {
        #pragma unroll
        for (int mf = 0; mf < 4; ++mf)
            #pragma unroll
            for (int r = 0; r < 4; ++r)
                red[wn][wm * 64 + mf * 16 + (lane >> 4) * 4 + r] = psum[mf][r];
    }
    __syncthreads();
    if (tid < 128) energy[m0 + tid] = red[0][tid] + red[1][tid];
}

// ---------------------------------------------------------------------------
// K4: softmax over l per b.  energy[l*64+b]
// ---------------------------------------------------------------------------
__global__ __launch_bounds__(256) void k_softmax_l(const float* __restrict__ energy,
                                                   float* __restrict__ attn_w) {
    int b = blockIdx.x;
    int tid = threadIdx.x;
    float el[4];
    float m = -1e30f;
    #pragma unroll
    for (int i = 0; i < 4; ++i) {
        int l = i * 256 + tid;
        float e = energy[l * 64 + b];
        el[i] = e;
        m = fmaxf(m, e);
    }
    #pragma unroll
    for (int s = 1; s < 64; s <<= 1) m = fmaxf(m, __shfl_xor(m, s));
    __shared__ float redm[4];
    if ((tid & 63) == 0) redm[tid >> 6] = m;
    __syncthreads();
    m = fmaxf(fmaxf(redm[0], redm[1]), fmaxf(redm[2], redm[3]));
    float s = 0.f;
    #pragma unroll
    for (int i = 0; i < 4; ++i) { el[i] = __expf(el[i] - m); s += el[i]; }
    #pragma unroll
    for (int sh = 1; sh < 64; sh <<= 1) s += __shfl_xor(s, sh);
    __shared__ float reds[4];
    if ((tid & 63) == 0) reds[tid >> 6] = s;
    __syncthreads();
    s = reds[0] + reds[1] + reds[2] + reds[3];
    float inv = 1.f / s;
    #pragma unroll
    for (int i = 0; i < 4; ++i)
        attn_w[(i * 256 + tid) * 64 + b] = el[i] * inv;
}

// ---------------------------------------------------------------------------
// K5: context partials over l chunks. grid (32 chunks, 64 b), thread = 2 h.
// ---------------------------------------------------------------------------
__global__ __launch_bounds__(256) void k_ctx_part(const float* __restrict__ attn_w,
                                                  const float* __restrict__ enc,
                                                  float* __restrict__ ctx_part) {
    int chunk = blockIdx.x, b = blockIdx.y;
    int h = threadIdx.x * 2;
    float2 acc = {0.f, 0.f};
    for (int i = 0; i < 32; ++i) {
        int l = chunk * 32 + i;
        float w = attn_w[l * 64 + b];
        float2 e2 = *reinterpret_cast<const float2*>(
            &enc[((size_t)l * 64 + b) * H + h]);
        acc.x += w * e2.x;
        acc.y += w * e2.y;
    }
    *reinterpret_cast<float2*>(&ctx_part[((size_t)(chunk * 64 + b)) * H + h]) = acc;
}

__global__ __launch_bounds__(256) void k_ctx_reduce(const float* __restrict__ ctx_part,
                                                    float* __restrict__ ctxT) {
    int gid = blockIdx.x * 256 + threadIdx.x;   // 0..32767
    int b = gid >> 9, h = gid & 511;
    float s = 0.f;
    for (int c = 0; c < 32; ++c)
        s += ctx_part[((size_t)(c * 64 + b)) * H + h];
    ctxT[h * 64 + b] = s;
}

// ---------------------------------------------------------------------------
// K6: co[b][j] = tanh([h | ctx] . W_oc[j] + b_oc[j])
// ---------------------------------------------------------------------------
__global__ __launch_bounds__(256) void k_co(const float* __restrict__ W_oc,
                                            const float* __restrict__ b_oc,
                                            const float* __restrict__ hT,
                                            const float* __restrict__ ctxT,
                                            float* __restrict__ co_out) {
    int j = blockIdx.x * 4 + (threadIdx.x >> 6);
    int b = threadIdx.x & 63;
    float acc = b_oc[j];
    const float* Wr = &W_oc[(size_t)j * (2 * H)];
    for (int k = 0; k < H; k += 4) {
        float4 wv = *reinterpret_cast<const float4*>(&Wr[k]);
        acc += wv.x * hT[(k + 0) * 64 + b];
        acc += wv.y * hT[(k + 1) * 64 + b];
        acc += wv.z * hT[(k + 2) * 64 + b];
        acc += wv.w * hT[(k + 3) * 64 + b];
    }
    const float* Wr2 = Wr + H;
    for (int k = 0; k < H; k += 4) {
        float4 wv = *reinterpret_cast<const float4*>(&Wr2[k]);
        acc += wv.x * ctxT[(k + 0) * 64 + b];
        acc += wv.y * ctxT[(k + 1) * 64 + b];
        acc += wv.z * ctxT[(k + 2) * 64 + b];
        acc += wv.w * ctxT[(k + 3) * 64 + b];
    }
    co_out[b * H + j] = tanhf(acc);
}

// ---------------------------------------------------------------------------
// K7: logits GEMM (fp32): logits[b][j] = co[b][:].W_out[j][:] + b_out[j]
// ---------------------------------------------------------------------------
#define KT 32
__global__ __launch_bounds__(256) void k_logits(const float* __restrict__ co,
                                                const float* __restrict__ W_out,
                                                const float* __restrict__ b_out,
                                                float* __restrict__ logits) {
    const int nb = blockIdx.x;          // 0..499
    const int tid = threadIdx.x;
    const int tx = tid & 15;
    const int ty = tid >> 4;
    __shared__ float As[KT][68];
    __shared__ float Bs[KT][68];
    float acc[4][4] = {};
    const int j0 = nb * 64;
    for (int k0 = 0; k0 < H; k0 += KT) {
        #pragma unroll
        for (int it = 0; it < 2; ++it) {
            int idx = tid + it * 256;
            int r  = idx >> 3;
            int c4 = idx & 7;
            float4 a = *reinterpret_cast<const float4*>(
                &co[(size_t)r * H + k0 + c4 * 4]);
            As[c4 * 4 + 0][r] = a.x; As[c4 * 4 + 1][r] = a.y;
            As[c4 * 4 + 2][r] = a.z; As[c4 * 4 + 3][r] = a.w;
            float4 w = *reinterpret_cast<const float4*>(
                &W_out[(size_t)(j0 + r) * H + k0 + c4 * 4]);
            Bs[c4 * 4 + 0][r] = w.x; Bs[c4 * 4 + 1][r] = w.y;
            Bs[c4 * 4 + 2][r] = w.z; Bs[c4 * 4 + 3][r] = w.w;
        }
        __syncthreads();
        #pragma unroll
        for (int k = 0; k < KT; ++k) {
            float4 a4 = *reinterpret_cast<const float4*>(&As[k][ty * 4]);
            float4 b4 = *reinterpret_cast<const float4*>(&Bs[k][tx * 4]);
            float a[4] = {a4.x, a4.y, a4.z, a4.w};
            float b[4] = {b4.x, b4.y, b4.z, b4.w};
            #pragma unroll
            for (int i = 0; i < 4; ++i)
                #pragma unroll
                for (int j = 0; j < 4; ++j)
                    acc[i][j] += a[i] * b[j];
        }
        __syncthreads();
    }
    #pragma unroll
    for (int i = 0; i < 4; ++i) {
        int b = ty * 4 + i;
        float4 v;
        v.x = acc[i][0] + b_out[j0 + tx * 4 + 0];
        v.y = acc[i][1] + b_out[j0 + tx * 4 + 1];
        v.z = acc[i][2] + b_out[j0 + tx * 4 + 2];
        v.w = acc[i][3] + b_out[j0 + tx * 4 + 3];
        *reinterpret_cast<float4*>(&logits[(size_t)b * V + j0 + tx * 4]) = v;
    }
}

// ---------------------------------------------------------------------------
// K8: log_softmax per b over V.
// ---------------------------------------------------------------------------
__global__ __launch_bounds__(1024) void k_logsm(const float* __restrict__ logits,
                                                float* __restrict__ out) {
    int b = blockIdx.x;
    int tid = threadIdx.x;
    const float* row = &logits[(size_t)b * V];
    float m = -1e30f;
    for (int i = tid; i < V; i += 1024) m = fmaxf(m, row[i]);
    #pragma unroll
    for (int s = 1; s < 64; s <<= 1) m = fmaxf(m, __shfl_xor(m, s));
    __shared__ float redm[16];
    if ((tid & 63) == 0) redm[tid >> 6] = m;
    __syncthreads();
    m = redm[0];
    #pragma unroll
    for (int i = 1; i < 16; ++i) m = fmaxf(m, redm[i]);
    float s = 0.f;
    for (int i = tid; i < V; i += 1024) s += __expf(row[i] - m);
    #pragma unroll
    for (int sh = 1; sh < 64; sh <<= 1) s += __shfl_xor(s, sh);
    __shared__ float reds[16];
    if ((tid & 63) == 0) reds[tid >> 6] = s;
    __syncthreads();
    s = reds[0];
    #pragma unroll
    for (int i = 1; i < 16; ++i) s += reds[i];
    float lse = m + __logf(s);
    for (int i = tid; i < V; i += 1024)
        out[(size_t)b * V + i] = row[i] - lse;
}

// ---------------------------------------------------------------------------
extern "C" void kernel_launch(void* const* d_in, const int* in_sizes, int n_in,
                              void* d_out, int out_size, void* d_ws, size_t ws_size,
                              hipStream_t stream) {
    const int*   inp    = (const int*)  d_in[0];
    const float* loc    = (const float*)d_in[1];
    const float* hprev  = (const float*)d_in[2];
    const float* cprev  = (const float*)d_in[3];
    const float* enc    = (const float*)d_in[4];
    const float* emb    = (const float*)d_in[5];
    const float* W_ih   = (const float*)d_in[6];
    const float* W_hh   = (const float*)d_in[7];
    const float* b_ih   = (const float*)d_in[8];
    const float* b_hh   = (const float*)d_in[9];
    const float* W_attn = (const float*)d_in[10];
    const float* b_attn = (const float*)d_in[11];
    const float* beta   = (const float*)d_in[12];
    const float* W_oc   = (const float*)d_in[13];
    const float* b_oc   = (const float*)d_in[14];
    const float* W_out  = (const float*)d_in[15];
    const float* b_out  = (const float*)d_in[16];

    float* out = (float*)d_out;
    float* out_co = out + (size_t)B * V;
    float* out_h  = out_co + B * H;
    float* out_c  = out_h  + B * H;

    float* ws = (float*)d_ws;
    float* xprevT = ws;                                  // 81920
    float* hnewT  = xprevT + 1280 * 64;                  // 32768
    float* hW     = hnewT  + H * 64;                     // 32768
    float* energy = hW     + H * 64;                     // 65536
    float* attnw  = energy + M_TOT;                      // 65536
    float* ctxp   = attnw  + M_TOT;                      // 32*64*512
    float* ctxT   = ctxp   + 32 * 64 * H;                // 32768
    float* logits = ctxT   + H * 64;                     // 64*32000

    k_build <<<320, 256, 0, stream>>>(inp, loc, hprev, emb, xprevT);
    k_lstm  <<<512, 256, 0, stream>>>(W_ih, W_hh, b_ih, b_hh, xprevT, cprev,
                                      out_h, out_c, hnewT);
    k_hw    <<<128, 256, 0, stream>>>(W_attn, b_attn, hnewT, hW);
    k_energy_mfma<<<512, 256, 0, stream>>>(enc, W_attn, hW, beta, energy);
    k_softmax_l<<<64, 256, 0, stream>>>(energy, attnw);
    k_ctx_part <<<dim3(32, 64), 256, 0, stream>>>(attnw, enc, ctxp);
    k_ctx_reduce<<<128, 256, 0, stream>>>(ctxp, ctxT);
    k_co    <<<128, 256, 0, stream>>>(W_oc, b_oc, hnewT, ctxT, out_co);
    k_logits<<<500, 256, 0, stream>>>(out_co, W_out, b_out, logits);
    k_logsm <<<64, 1024, 0, stream>>>(logits, out);
}